// Round 3
// baseline (58.019 us; speedup 1.0000x reference)
//
#include <hip/hip_runtime.h>
#include <hip/hip_bf16.h>
#include <stdint.h>

#define B_   32
#define N_   128
#define E_   8192
#define IMG_ 2048
#define H_   128

typedef __attribute__((ext_vector_type(8))) short bf16x8;
typedef __attribute__((ext_vector_type(4))) float f32x4;

__device__ inline uint16_t f2bf(float x) {
    uint32_t u = __float_as_uint(x);
    uint32_t r = (u + 0x7FFFu + ((u >> 16) & 1u)) >> 16;
    return (uint16_t)r;
}
__device__ inline float bf2f(short x) {
    return __uint_as_float(((uint32_t)(uint16_t)x) << 16);
}

// ---------------------------------------------------------------------------
// P: weight transpose+convert to bf16 k-major.
// blocks 0..31: W_img via LDS transpose (coalesced read AND write).
// blocks 32..159: W_rel strided (tiny, L2-resident).
// ---------------------------------------------------------------------------
__global__ __launch_bounds__(256) void prep_kernel(
    const float* __restrict__ W_img, const float* __restrict__ W_rel,
    uint16_t* __restrict__ Wt_img, uint16_t* __restrict__ Wt_rel) {
    int bid = blockIdx.x, tid = threadIdx.x;
    if (bid < 32) {
        __shared__ float t[64][129];
        int k0 = bid * 64;
        const float* src = W_img + (size_t)k0 * H_;
        #pragma unroll
        for (int it = 0; it < 32; it++) {
            int idx = it * 256 + tid;            // 0..8191 over [64k][128c]
            t[idx >> 7][idx & 127] = src[idx];
        }
        __syncthreads();
        int c = tid >> 1, kh = (tid & 1) * 32;
        uint16_t* dst = Wt_img + (size_t)c * IMG_ + k0 + kh;
        #pragma unroll
        for (int j = 0; j < 32; j++) dst[j] = f2bf(t[kh + j][c]);
    } else {
        int t2 = (bid - 32) * 256 + tid;         // 0..32767
        int c = t2 >> 8, k = t2 & 255;
        Wt_rel[t2] = f2bf(W_rel[k * H_ + c]);
    }
}

// ---------------------------------------------------------------------------
// NODE+PROJ fused. Grid 256 x 1024 thr (16 waves), strip = 16 rows.
// Stage: whole 16x2048 fp32 A-strip (128 KB, contiguous in global) ->
//        LDS via global_load_lds width=16, source XOR-pre-swizzled
//        (koff ^ ((row&7)<<4)) so swizzled ds_read_b128 is conflict-free.
// Phase 1: wave w = K-slice of 128; B-frags reg-prefetched (rotated).
// Phase 2: partials -> red (aliases A-tile; barrier first).
// Phase 3: 16-way reduce + b_img + loc path -> node_feat; bf16 img -> imgb.
// Phase 4: proj GEMM K=128 -> proj[4096][256] bf16 (b_rel folded, src half).
// ---------------------------------------------------------------------------
__global__ __launch_bounds__(1024) void node_proj_kernel(
    const float* __restrict__ img_feat,
    const uint16_t* __restrict__ Wt_img,
    const uint16_t* __restrict__ Wt_rel,
    const float* __restrict__ img_loc,
    const float* __restrict__ b_img,
    const float* __restrict__ W_loc,
    const float* __restrict__ b_loc,
    const float* __restrict__ b_rel,
    float* __restrict__ out_node,
    uint16_t* __restrict__ proj) {
    __shared__ __align__(16) char lds_raw[131072];
    float (*red)[16][128] = (float (*)[16][128])lds_raw;     // aliases A-tile
    uint16_t (*imgb)[136] = (uint16_t (*)[136])lds_raw;      // aliases too

    int strip = blockIdx.x;
    int tid = threadIdx.x;
    int w  = tid >> 6;       // wave 0..15 = K-slice
    int l  = tid & 63;
    int lr = l & 15;
    int kq = l >> 4;

    // ---- stage A: 8 x 16B per thread, linear LDS dest, swizzled source ----
    const char* gA = (const char*)(img_feat + (size_t)strip * 16 * IMG_);
    #pragma unroll
    for (int r = 0; r < 8; r++) {
        int L = r * 16384 + tid * 16;            // linear LDS byte
        int row = L >> 13;                       // 8 KB per fp32 row
        int koff = L & 8191;
        int gsrc = row * 8192 + (koff ^ ((row & 7) << 4));
        __builtin_amdgcn_global_load_lds(
            (const __attribute__((address_space(1))) void*)(gA + gsrc),
            (__attribute__((address_space(3))) void*)(lds_raw + L), 16, 0, 0);
    }

    // ---- prefetch B for ks=0 (overlaps staging; drained by the barrier) ----
    int kbase = w * 128 + kq * 8;
    bf16x8 bcur[8];
    #pragma unroll
    for (int n = 0; n < 8; n++)
        bcur[n] = *(const bf16x8*)(Wt_img + (size_t)(n * 16 + lr) * IMG_ + kbase);

    __syncthreads();   // drains vmcnt: A-tile in LDS, bcur in regs

    // ---- phase 1: K-slice GEMM from LDS ----
    f32x4 acc[8];
    #pragma unroll
    for (int n = 0; n < 8; n++) acc[n] = (f32x4){0.f, 0.f, 0.f, 0.f};
    int sw = (lr & 7) << 4;
    #pragma unroll
    for (int ks = 0; ks < 4; ks++) {
        int koffb = w * 512 + ks * 128 + kq * 32;   // byte offset within row
        float4 a0 = *(const float4*)(lds_raw + (size_t)lr * 8192 + (koffb ^ sw));
        float4 a1 = *(const float4*)(lds_raw + (size_t)lr * 8192 + ((koffb + 16) ^ sw));
        bf16x8 bn[8];
        if (ks < 3) {
            int kn = kbase + (ks + 1) * 32;
            #pragma unroll
            for (int n = 0; n < 8; n++)
                bn[n] = *(const bf16x8*)(Wt_img + (size_t)(n * 16 + lr) * IMG_ + kn);
        }
        bf16x8 af;
        af[0] = (short)f2bf(a0.x); af[1] = (short)f2bf(a0.y);
        af[2] = (short)f2bf(a0.z); af[3] = (short)f2bf(a0.w);
        af[4] = (short)f2bf(a1.x); af[5] = (short)f2bf(a1.y);
        af[6] = (short)f2bf(a1.z); af[7] = (short)f2bf(a1.w);
        #pragma unroll
        for (int n = 0; n < 8; n++)
            acc[n] = __builtin_amdgcn_mfma_f32_16x16x32_bf16(af, bcur[n], acc[n], 0, 0, 0);
        if (ks < 3) {
            #pragma unroll
            for (int n = 0; n < 8; n++) bcur[n] = bn[n];
        }
    }
    __syncthreads();   // all A-tile reads done before red overwrites it

    // ---- phase 2: dump partials ----
    #pragma unroll
    for (int n = 0; n < 8; n++)
        #pragma unroll
        for (int r = 0; r < 4; r++)
            red[w][kq * 4 + r][n * 16 + lr] = acc[n][r];
    __syncthreads();

    // ---- phase 3: reduce + epilogue ----
    int row0 = tid >> 7, col = tid & 127;    // rows 0..7
    int row1 = row0 + 8;                     // rows 8..15
    float s0 = 0.f, s1 = 0.f;
    #pragma unroll
    for (int ww = 0; ww < 16; ww++) {
        s0 += red[ww][row0][col];
        s1 += red[ww][row1][col];
    }
    __syncthreads();   // red reads done before imgb overwrites

    {
        float bi = b_img[col];
        float bl = b_loc[col];
        float wl[5];
        #pragma unroll
        for (int j = 0; j < 5; j++) wl[j] = W_loc[j * H_ + col];
        float img0 = s0 + bi, img1 = s1 + bi;
        int g0 = strip * 16 + row0, g1 = strip * 16 + row1;
        const float* lc0 = img_loc + g0 * 5;
        const float* lc1 = img_loc + g1 * 5;
        float loc0 = bl, loc1 = bl;
        #pragma unroll
        for (int j = 0; j < 5; j++) { loc0 += lc0[j] * wl[j]; loc1 += lc1[j] * wl[j]; }
        out_node[(size_t)g0 * H_ + col] = img0 + loc0;
        out_node[(size_t)g1 * H_ + col] = img1 + loc1;
        imgb[row0][col] = f2bf(img0);
        imgb[row1][col] = f2bf(img1);
    }
    __syncthreads();   // imgb visible

    // ---- phase 4: proj GEMM (K=128, 256 cols; wave w -> cols w*16..w*16+15)
    int kl = kq * 8;
    int cp = w * 16 + lr;
    const uint16_t* bbase = (cp < 128)
        ? (Wt_rel + (size_t)cp * 256)
        : (Wt_rel + (size_t)(cp - 128) * 256 + 128);
    f32x4 pacc = (f32x4){0.f, 0.f, 0.f, 0.f};
    #pragma unroll
    for (int ks = 0; ks < 4; ks++) {
        int k = ks * 32 + kl;
        bf16x8 af = *(const bf16x8*)(&imgb[lr][k]);
        bf16x8 bf = *(const bf16x8*)(bbase + k);
        pacc = __builtin_amdgcn_mfma_f32_16x16x32_bf16(af, bf, pacc, 0, 0, 0);
    }
    float brel = (cp < 128) ? b_rel[cp] : 0.f;
    #pragma unroll
    for (int r = 0; r < 4; r++) {
        int grow = strip * 16 + kq * 4 + r;
        proj[(size_t)grow * 256 + cp] = f2bf(pacc[r] + brel);
    }
}

// ---------------------------------------------------------------------------
// EDGE stream: out[b,e,c] = proj[b*128+src[e]][c] + proj[b*128+dst[e]][128+c]
// ---------------------------------------------------------------------------
__global__ __launch_bounds__(256) void edge_kernel(
    const uint16_t* __restrict__ proj,
    const int* __restrict__ edge_src,
    const int* __restrict__ edge_dst,
    float* __restrict__ out_edge) {
    int t = blockIdx.x * 256 + threadIdx.x;     // 524288 threads
    #pragma unroll
    for (int it = 0; it < 8; it++) {
        int g = t + it * 524288;
        int b = g >> 17;
        int r = g & 131071;
        int e = r >> 4;
        int c = (r & 15) * 8;
        int s = edge_src[e];
        int d = edge_dst[e];
        bf16x8 a  = *(const bf16x8*)(proj + (((size_t)b * N_ + s) * 256 + c));
        bf16x8 bb = *(const bf16x8*)(proj + (((size_t)b * N_ + d) * 256 + 128 + c));
        float* op = out_edge + ((size_t)b * E_ + e) * (size_t)H_ + c;
        float4 o0, o1;
        o0.x = bf2f(a[0]) + bf2f(bb[0]);
        o0.y = bf2f(a[1]) + bf2f(bb[1]);
        o0.z = bf2f(a[2]) + bf2f(bb[2]);
        o0.w = bf2f(a[3]) + bf2f(bb[3]);
        o1.x = bf2f(a[4]) + bf2f(bb[4]);
        o1.y = bf2f(a[5]) + bf2f(bb[5]);
        o1.z = bf2f(a[6]) + bf2f(bb[6]);
        o1.w = bf2f(a[7]) + bf2f(bb[7]);
        *(float4*)op = o0;
        *(float4*)(op + 4) = o1;
    }
}

// ---------------------------------------------------------------------------
extern "C" void kernel_launch(void* const* d_in, const int* in_sizes, int n_in,
                              void* d_out, int out_size, void* d_ws, size_t ws_size,
                              hipStream_t stream) {
    const float* img_feat = (const float*)d_in[0];
    const float* img_loc  = (const float*)d_in[1];
    const int*   edge_src = (const int*)d_in[2];
    const int*   edge_dst = (const int*)d_in[3];
    const float* W_img    = (const float*)d_in[4];
    const float* b_img    = (const float*)d_in[5];
    const float* W_loc    = (const float*)d_in[6];
    const float* b_loc    = (const float*)d_in[7];
    const float* W_rel    = (const float*)d_in[8];
    const float* b_rel    = (const float*)d_in[9];

    float* out_node = (float*)d_out;                       // [B,N,H]
    float* out_edge = out_node + (size_t)B_ * N_ * H_;     // [B,E,H]

    char* ws = (char*)d_ws;
    uint16_t* Wt_img = (uint16_t*)ws;                      // 512 KB
    uint16_t* Wt_rel = (uint16_t*)(ws + 524288);           // 64 KB
    uint16_t* proj   = (uint16_t*)(ws + 524288 + 65536);   // 2 MB [4096][256]

    prep_kernel<<<dim3(160), dim3(256), 0, stream>>>(W_img, W_rel, Wt_img, Wt_rel);

    node_proj_kernel<<<dim3(256), dim3(1024), 0, stream>>>(
        img_feat, Wt_img, Wt_rel, img_loc, b_img, W_loc, b_loc, b_rel,
        out_node, proj);

    edge_kernel<<<dim3(2048), dim3(256), 0, stream>>>(
        proj, edge_src, edge_dst, out_edge);
}